// Round 3
// baseline (1905.107 us; speedup 1.0000x reference)
//
#include <hip/hip_runtime.h>

typedef unsigned short u16;
typedef float f32x4 __attribute__((ext_vector_type(4)));
typedef int   i32x4 __attribute__((ext_vector_type(4)));
typedef short bf16x8 __attribute__((ext_vector_type(8)));

#define CCH    192
#define HW     16384
#define NPIX   131072          // B*H*W
#define NELEM  25165824        // NPIX*CCH
#define NSAMP  3145728         // CCH*HW (per-sample GroupNorm count)

__device__ __forceinline__ float b2f(u16 u) {
  return __uint_as_float(((unsigned)u) << 16);
}
__device__ __forceinline__ u16 f2b(float f) {
  unsigned u = __float_as_uint(f);
  unsigned r = (u + 0x7fffu + ((u >> 16) & 1u)) >> 16;   // RNE
  return (u16)r;
}
__device__ __forceinline__ void unpack8(i32x4 v, float* f) {
#pragma unroll
  for (int i = 0; i < 4; i++) {
    unsigned u = (unsigned)v[i];
    f[2 * i]     = __uint_as_float(u << 16);
    f[2 * i + 1] = __uint_as_float(u & 0xffff0000u);
  }
}
__device__ __forceinline__ i32x4 pack8(const float* f) {
  i32x4 r;
#pragma unroll
  for (int i = 0; i < 4; i++) {
    unsigned lo = f2b(f[2 * i]);
    unsigned hi = f2b(f[2 * i + 1]);
    r[i] = (int)(lo | (hi << 16));
  }
  return r;
}

// ---------------------------------------------------------------- stats ----
// fp32 NCHW input; per-sample sum / sumsq via atomics.
__global__ __launch_bounds__(256) void stats_partial(
    const float* __restrict__ A, const float* __restrict__ B,
    float* __restrict__ acc, int slotbase) {
  const float* src = (blockIdx.z == 0) ? A : B;
  int sample = blockIdx.y;
  size_t base = (size_t)sample * NSAMP + (size_t)blockIdx.x * 32768;
  float s = 0.f, q = 0.f;
  for (int it = 0; it < 16; it++) {
    const float* ptr = src + base + it * 2048 + threadIdx.x * 8;
    f32x4 v0 = *(const f32x4*)ptr;
    f32x4 v1 = *(const f32x4*)(ptr + 4);
#pragma unroll
    for (int i = 0; i < 4; i++) {
      s += v0[i] + v1[i];
      q += v0[i] * v0[i] + v1[i] * v1[i];
    }
  }
#pragma unroll
  for (int o = 32; o > 0; o >>= 1) {
    s += __shfl_down(s, o);
    q += __shfl_down(q, o);
  }
  __shared__ float red[8];
  int wv = threadIdx.x >> 6;
  if ((threadIdx.x & 63) == 0) { red[wv * 2] = s; red[wv * 2 + 1] = q; }
  __syncthreads();
  if (threadIdx.x == 0) {
    float S = red[0] + red[2] + red[4] + red[6];
    float Q = red[1] + red[3] + red[5] + red[7];
    int e = ((slotbase + blockIdx.z) * 8 + sample) * 2;
    atomicAdd(&acc[e], S);
    atomicAdd(&acc[e + 1], Q);
  }
}

__global__ void finalize_stats(const float* __restrict__ acc,
                               float* __restrict__ mr, int entbase, int nent) {
  int i = threadIdx.x;
  if (i < nent) {
    int e = entbase + i;
    float s = acc[e * 2], q = acc[e * 2 + 1];
    const float invN = 1.0f / (float)NSAMP;
    float mean = s * invN;
    float var = q * invN - mean * mean;
    mr[e * 2] = mean;
    mr[e * 2 + 1] = rsqrtf(var + 1e-5f);
  }
}

// ------------------------------- groupnorm + NCHW(fp32) -> NHWC(bf16) ------
__global__ __launch_bounds__(256) void norm_t(
    const float* __restrict__ in, u16* __restrict__ outp,
    const float* __restrict__ g, const float* __restrict__ bb,
    const float* __restrict__ mr, int slot) {
  __shared__ u16 tile[128 * 201];   // [x][c], stride 201 to break conflicts
  int yy = blockIdx.x, b = blockIdx.y;
  int e = (slot * 8 + b) * 2;
  float mean = mr[e], rstd = mr[e + 1];
  int tid = threadIdx.x;
  for (int task = tid; task < 3072; task += 256) {   // 192 c x 16 xchunks
    int c = task >> 4, xc = task & 15;
    const float* p = in + (size_t)(b * CCH + c) * HW + yy * 128 + xc * 8;
    f32x4 v0 = *(const f32x4*)p;
    f32x4 v1 = *(const f32x4*)(p + 4);
    float sc = rstd * g[c];
    float of = bb[c] - mean * sc;
#pragma unroll
    for (int i = 0; i < 4; i++) {
      tile[(xc * 8 + i) * 201 + c]       = f2b(v0[i] * sc + of);
      tile[(xc * 8 + 4 + i) * 201 + c]   = f2b(v1[i] * sc + of);
    }
  }
  __syncthreads();
  size_t ob = ((size_t)b * HW + (size_t)yy * 128) * CCH;
  for (int task = tid; task < 3072; task += 256) {   // 128 x x 24 cchunks
    int xx = task / 24, cc = task % 24;
    i32x4 v;
#pragma unroll
    for (int i = 0; i < 4; i++) {
      unsigned lo = tile[xx * 201 + cc * 8 + 2 * i];
      unsigned hi = tile[xx * 201 + cc * 8 + 2 * i + 1];
      v[i] = (int)(lo | (hi << 16));
    }
    *(i32x4*)(outp + ob + (size_t)xx * CCH + cc * 8) = v;
  }
}

// ------------------------------------------------------------ attention ----
// One block per window; wave h handles head h; lane = token (8x8 row-major).
// qkv (bf16, internal) -> out (bf16, internal). fp32 softmax, logits clamped.
__global__ __launch_bounds__(256) void attn_kernel(
    const u16* __restrict__ qkv, const float* __restrict__ relb,
    u16* __restrict__ outp) {
  __shared__ u16 kbuf[64 * 200];
  __shared__ u16 vbuf[64 * 200];
  __shared__ float btab[900];
  int tid = threadIdx.x;
  int h = tid >> 6, t = tid & 63;
  int win = blockIdx.x;
  int b = win >> 8, wy = (win >> 4) & 15, wx = win & 15;
  int ty = t >> 3, tx = t & 7;
  int y = wy * 8 + ty, x = wx * 8 + tx;
  int p = (b << 14) + y * 128 + x;
  for (int i = tid; i < 900; i += 256) btab[i] = relb[i];
  const u16* qp = qkv + (size_t)p * 576 + h * 48;
  float qreg[48];
#pragma unroll
  for (int c = 0; c < 6; c++) {
    i32x4 v = *(const i32x4*)(qp + c * 8);
    unpack8(v, &qreg[c * 8]);
  }
  const float scale = 0.14433756729740643f;   // 48^-0.5
#pragma unroll
  for (int i = 0; i < 48; i++) qreg[i] *= scale;
  int rb = t * 200 + h * 48;
#pragma unroll
  for (int c = 0; c < 6; c++) {
    *(i32x4*)&kbuf[rb + c * 8] = *(const i32x4*)(qp + 192 + c * 8);
    *(i32x4*)&vbuf[rb + c * 8] = *(const i32x4*)(qp + 384 + c * 8);
  }
  __syncthreads();
  float oacc[48];
#pragma unroll
  for (int i = 0; i < 48; i++) oacc[i] = 0.f;
  float l = 0.f;
  int hb = h * 225 + (ty + 7) * 15 + tx + 7;   // bias idx = hb - jy*15 - jx
  for (int j = 0; j < 64; j++) {
    const u16* kr = &kbuf[j * 200 + h * 48];
    float s0 = 0.f, s1 = 0.f, s2 = 0.f, s3 = 0.f;
#pragma unroll
    for (int c = 0; c < 6; c++) {
      i32x4 kv = *(const i32x4*)(kr + c * 8);
      float kf[8];
      unpack8(kv, kf);
      s0 += qreg[c * 8 + 0] * kf[0]; s1 += qreg[c * 8 + 1] * kf[1];
      s2 += qreg[c * 8 + 2] * kf[2]; s3 += qreg[c * 8 + 3] * kf[3];
      s0 += qreg[c * 8 + 4] * kf[4]; s1 += qreg[c * 8 + 5] * kf[5];
      s2 += qreg[c * 8 + 6] * kf[6]; s3 += qreg[c * 8 + 7] * kf[7];
    }
    int jy = j >> 3, jx = j & 7;
    float sv = (s0 + s1) + (s2 + s3) + btab[hb - jy * 15 - jx];
    sv = fminf(fmaxf(sv, -60.f), 60.f);
    float e = __expf(sv);
    l += e;
    const u16* vr = &vbuf[j * 200 + h * 48];
#pragma unroll
    for (int c = 0; c < 6; c++) {
      i32x4 vv = *(const i32x4*)(vr + c * 8);
      float vf[8];
      unpack8(vv, vf);
#pragma unroll
      for (int i2 = 0; i2 < 8; i2++) oacc[c * 8 + i2] += e * vf[i2];
    }
  }
  float rl = 1.0f / l;
  u16* op = outp + (size_t)p * CCH + h * 48;
#pragma unroll
  for (int c = 0; c < 6; c++) {
    float f[8];
#pragma unroll
    for (int i2 = 0; i2 < 8; i2++) f[i2] = oacc[c * 8 + i2] * rl;
    *(i32x4*)(op + c * 8) = pack8(f);
  }
}

// ----------------------------------------------------------------- GEMM ----
// C[p,o] = sum_k X[p,k]*W[o,k]
// X: internal bf16 NHWC [P][K].  W: fp32 row-major [O][K] (converted to bf16
// in staging).  bias fp32.
// GM_BIAS: out bf16 [P][O]            (qkv)
// GM_GATE: out bf16 = aux(bf16) + scale*sigmoid(y)   (cross-gating)
// GM_GELU: out bf16 = gelu(y)         (ffn1)
// GM_RES : out fp32 NCHW = aux(fp32 NCHW) + y + bias (proj/ffn2 residual)
enum { GM_BIAS = 0, GM_GATE = 1, GM_GELU = 2, GM_RES = 3 };

struct SmemGemm {
  union {
    struct { u16 xs[64 * 72]; u16 ws[64 * 72]; } s;   // staged tiles, pad 72
    float y[64 * 72];                                 // epilogue repack tile
  };
};

template <int MODE>
__global__ __launch_bounds__(256) void gemm_kernel(
    const u16* __restrict__ X, const float* __restrict__ W,
    const float* __restrict__ bias, const void* aux,
    void* outv, const float* __restrict__ scale_ptr, int K, int O) {
  __shared__ SmemGemm sm;
  int tid = threadIdx.x;
  int p0 = blockIdx.x * 64;
  int o0 = blockIdx.y * 64;
  int lane = tid & 63, wave = tid >> 6;
  int l15 = lane & 15, q8 = lane >> 4;
  int wm = (wave & 1) * 32, wn = (wave >> 1) * 32;

  f32x4 acc[2][2];
#pragma unroll
  for (int i = 0; i < 2; i++)
#pragma unroll
    for (int j = 0; j < 2; j++) {
      f32x4 z = {0.f, 0.f, 0.f, 0.f};
      acc[i][j] = z;
    }

  int srow = tid >> 2;            // 0..63
  int scol = (tid & 3) * 16;      // 0,16,32,48
  const u16* xg   = X + (size_t)(p0 + srow) * K + scol;
  const float* wg = W + (size_t)(o0 + srow) * K + scol;
  u16* xst = &sm.s.xs[srow * 72 + scol];
  u16* wst = &sm.s.ws[srow * 72 + scol];

  for (int k0 = 0; k0 < K; k0 += 64) {
    __syncthreads();
    i32x4 x0 = *(const i32x4*)xg;
    i32x4 x1 = *(const i32x4*)(xg + 8);
    f32x4 wv0 = *(const f32x4*)wg;
    f32x4 wv1 = *(const f32x4*)(wg + 4);
    f32x4 wv2 = *(const f32x4*)(wg + 8);
    f32x4 wv3 = *(const f32x4*)(wg + 12);
    xg += 64; wg += 64;
    float wf[16];
#pragma unroll
    for (int i = 0; i < 4; i++) {
      wf[i] = wv0[i]; wf[4 + i] = wv1[i]; wf[8 + i] = wv2[i]; wf[12 + i] = wv3[i];
    }
    *(i32x4*)xst = x0;
    *(i32x4*)(xst + 8) = x1;
    *(i32x4*)wst = pack8(wf);
    *(i32x4*)(wst + 8) = pack8(wf + 8);
    __syncthreads();
#pragma unroll
    for (int s = 0; s < 2; s++) {
      bf16x8 a0 = *(const bf16x8*)&sm.s.xs[(wm + l15) * 72 + s * 32 + q8 * 8];
      bf16x8 a1 = *(const bf16x8*)&sm.s.xs[(wm + 16 + l15) * 72 + s * 32 + q8 * 8];
      bf16x8 b0 = *(const bf16x8*)&sm.s.ws[(wn + l15) * 72 + s * 32 + q8 * 8];
      bf16x8 b1 = *(const bf16x8*)&sm.s.ws[(wn + 16 + l15) * 72 + s * 32 + q8 * 8];
      acc[0][0] = __builtin_amdgcn_mfma_f32_16x16x32_bf16(a0, b0, acc[0][0], 0, 0, 0);
      acc[0][1] = __builtin_amdgcn_mfma_f32_16x16x32_bf16(a0, b1, acc[0][1], 0, 0, 0);
      acc[1][0] = __builtin_amdgcn_mfma_f32_16x16x32_bf16(a1, b0, acc[1][0], 0, 0, 0);
      acc[1][1] = __builtin_amdgcn_mfma_f32_16x16x32_bf16(a1, b1, acc[1][1], 0, 0, 0);
    }
  }
  __syncthreads();
  // C/D layout: col(o) = lane&15, row(p) = (lane>>4)*4 + reg
#pragma unroll
  for (int mi = 0; mi < 2; mi++) {
#pragma unroll
    for (int ni = 0; ni < 2; ni++) {
      int pl = wm + mi * 16 + q8 * 4;
      int ol = wn + ni * 16 + l15;
#pragma unroll
      for (int r = 0; r < 4; r++) {
        float v = acc[mi][ni][r];
        if (MODE == GM_RES) sm.y[ol * 72 + pl + r] = v;       // [o][p]
        else                sm.y[(pl + r) * 72 + ol] = v;     // [p][o]
      }
    }
  }
  __syncthreads();
  if (MODE == GM_RES) {
    const float* auxf = (const float*)aux;
    float* outf = (float*)outv;
    int o = tid >> 2;
    int pc = (tid & 3) * 16;
    float vals[16];
#pragma unroll
    for (int i = 0; i < 16; i++) vals[i] = sm.y[o * 72 + pc + i];
    int og = o0 + o;
    int pg = p0 + pc;
    int bi = pg >> 14;
    int r = pg & (HW - 1);
    size_t idx = ((size_t)(bi * CCH + og) << 14) + r;
    float bv = bias[og];
    f32x4 res[4];
#pragma unroll
    for (int i = 0; i < 4; i++) res[i] = *(const f32x4*)(auxf + idx + i * 4);
#pragma unroll
    for (int i = 0; i < 4; i++) {
      f32x4 w;
#pragma unroll
      for (int j = 0; j < 4; j++) w[j] = res[i][j] + vals[i * 4 + j] + bv;
      *(f32x4*)(outf + idx + i * 4) = w;
    }
  } else {
    u16* outb = (u16*)outv;
    const u16* auxb = (const u16*)aux;
    int pl = tid >> 2;
    int oc = (tid & 3) * 16;
    float vals[16];
#pragma unroll
    for (int i = 0; i < 16; i++) vals[i] = sm.y[pl * 72 + oc + i];
    int og0 = o0 + oc;
    size_t rowb = (size_t)(p0 + pl) * (size_t)O + og0;
    float sc = 0.f;
    if (MODE == GM_GATE) sc = scale_ptr[0];
    float f[16];
#pragma unroll
    for (int i = 0; i < 16; i++) {
      float v = vals[i] + bias[og0 + i];
      if (MODE == GM_GATE) {
        float sg = 1.0f / (1.0f + __expf(-v));
        v = b2f(auxb[rowb + i]) + sc * sg;
      } else if (MODE == GM_GELU) {
        v = 0.5f * v * (1.0f + erff(v * 0.70710678118654752f));
      }
      f[i] = v;
    }
    *(i32x4*)(outb + rowb) = pack8(f);
    *(i32x4*)(outb + rowb + 8) = pack8(f + 8);
  }
}

// --------------------------------------------------------------- launch ----
extern "C" void kernel_launch(void* const* d_in, const int* in_sizes, int n_in,
                              void* d_out, int out_size, void* d_ws,
                              size_t ws_size, hipStream_t stream) {
  (void)in_sizes; (void)n_in; (void)out_size; (void)ws_size;
  const float* sem       = (const float*)d_in[0];
  const float* dep       = (const float*)d_in[1];
  const float* ns_g      = (const float*)d_in[2];
  const float* ns_b      = (const float*)d_in[3];
  const float* nd_g      = (const float*)d_in[4];
  const float* nd_b      = (const float*)d_in[5];
  const float* wd2s      = (const float*)d_in[6];
  const float* bd2s      = (const float*)d_in[7];
  const float* ws2d      = (const float*)d_in[8];
  const float* bs2d      = (const float*)d_in[9];
  const float* alpha     = (const float*)d_in[10];
  const float* beta      = (const float*)d_in[11];
  const float* qkv_sem_w = (const float*)d_in[12];
  const float* qkv_sem_b = (const float*)d_in[13];
  const float* out_sem_w = (const float*)d_in[14];
  const float* out_sem_b = (const float*)d_in[15];
  const float* qkv_dep_w = (const float*)d_in[16];
  const float* qkv_dep_b = (const float*)d_in[17];
  const float* out_dep_w = (const float*)d_in[18];
  const float* out_dep_b = (const float*)d_in[19];
  const float* relb      = (const float*)d_in[20];
  const float* fs_g      = (const float*)d_in[21];
  const float* fs_b      = (const float*)d_in[22];
  const float* fs_w1     = (const float*)d_in[23];
  const float* fs_b1     = (const float*)d_in[24];
  const float* fs_w2     = (const float*)d_in[25];
  const float* fs_b2     = (const float*)d_in[26];
  const float* fd_g      = (const float*)d_in[27];
  const float* fd_b      = (const float*)d_in[28];
  const float* fd_w1     = (const float*)d_in[29];
  const float* fd_b1     = (const float*)d_in[30];
  const float* fd_w2     = (const float*)d_in[31];
  const float* fd_b2     = (const float*)d_in[32];

  float* stats_acc = (float*)d_ws;                       // 64 f32
  float* mr        = (float*)((char*)d_ws + 256);        // 64 f32
  u16* R1 = (u16*)((char*)d_ws + 1024);                  // 4x 50.3MB bf16 NHWC
  u16* R2 = R1 + NELEM;
  u16* R3 = R2 + NELEM;
  u16* R4 = R3 + NELEM;
  u16* R5 = R4 + NELEM;                                  // 151MB qkv / ffn-hid
  float* outS = (float*)d_out;                           // fp32 NCHW outputs
  float* outD = outS + NELEM;

  hipMemsetAsync(d_ws, 0, 512, stream);
  // GroupNorm stats on raw inputs
  stats_partial<<<dim3(96, 8, 2), 256, 0, stream>>>(sem, dep, stats_acc, 0);
  finalize_stats<<<1, 64, 0, stream>>>(stats_acc, mr, 0, 16);
  norm_t<<<dim3(128, 8), 256, 0, stream>>>(sem, R1, ns_g, ns_b, mr, 0);
  norm_t<<<dim3(128, 8), 256, 0, stream>>>(dep, R2, nd_g, nd_b, mr, 1);
  // cross-gating: sem_in = semn + a*sig(conv(depn)), dep_in = depn + b*sig(conv(semn))
  gemm_kernel<GM_GATE><<<dim3(2048, 3), 256, 0, stream>>>(R2, wd2s, bd2s, R1, R3, alpha, 192, 192);
  gemm_kernel<GM_GATE><<<dim3(2048, 3), 256, 0, stream>>>(R1, ws2d, bs2d, R2, R4, beta, 192, 192);
  // sem stream: qkv -> attn -> outproj(+residual, fp32 NCHW)
  gemm_kernel<GM_BIAS><<<dim3(2048, 9), 256, 0, stream>>>(R3, qkv_sem_w, qkv_sem_b, nullptr, R5, nullptr, 192, 576);
  attn_kernel<<<2048, 256, 0, stream>>>(R5, relb, R2);
  gemm_kernel<GM_RES><<<dim3(2048, 3), 256, 0, stream>>>(R2, out_sem_w, out_sem_b, sem, outS, nullptr, 192, 192);
  // dep stream
  gemm_kernel<GM_BIAS><<<dim3(2048, 9), 256, 0, stream>>>(R4, qkv_dep_w, qkv_dep_b, nullptr, R5, nullptr, 192, 576);
  attn_kernel<<<2048, 256, 0, stream>>>(R5, relb, R2);
  gemm_kernel<GM_RES><<<dim3(2048, 3), 256, 0, stream>>>(R2, out_dep_w, out_dep_b, dep, outD, nullptr, 192, 192);
  // FFN: gn -> conv1+gelu -> conv2 (+residual into d_out, fp32)
  stats_partial<<<dim3(96, 8, 2), 256, 0, stream>>>(outS, outD, stats_acc, 2);
  finalize_stats<<<1, 64, 0, stream>>>(stats_acc, mr, 16, 16);
  norm_t<<<dim3(128, 8), 256, 0, stream>>>(outS, R1, fs_g, fs_b, mr, 2);
  norm_t<<<dim3(128, 8), 256, 0, stream>>>(outD, R3, fd_g, fd_b, mr, 3);
  gemm_kernel<GM_GELU><<<dim3(2048, 6), 256, 0, stream>>>(R1, fs_w1, fs_b1, nullptr, R5, nullptr, 192, 384);
  gemm_kernel<GM_RES><<<dim3(2048, 3), 256, 0, stream>>>(R5, fs_w2, fs_b2, outS, outS, nullptr, 384, 192);
  gemm_kernel<GM_GELU><<<dim3(2048, 6), 256, 0, stream>>>(R3, fd_w1, fd_b1, nullptr, R5, nullptr, 192, 384);
  gemm_kernel<GM_RES><<<dim3(2048, 3), 256, 0, stream>>>(R5, fd_w2, fd_b2, outD, outD, nullptr, 384, 192);
}